// Round 2
// baseline (2083.109 us; speedup 1.0000x reference)
//
#include <hip/hip_runtime.h>
#include <math.h>

#define TT 2048
#define BBATCH 256
#define DDIM 57
#define NROWS (BBATCH*TT)
#define NF 524288.0f

__device__ __forceinline__ float bcastl(float v, int k) {
  // wave-wide broadcast of lane k's value via the scalar pipe (SGPR result)
  return __uint_as_float((unsigned)__builtin_amdgcn_readlane((int)__float_as_uint(v), k));
}
__device__ __forceinline__ float rcpf(float x) { return __builtin_amdgcn_rcpf(x); }

__global__ void zero_accum_k(float* accum) {
  accum[threadIdx.x] = 0.f;
}

// xg0[r, g] = sum_d x[r,d] * W_ih0[g,d] + (b_ih0[g] + b_hh0[g])
// one wave per row batch (grid-stride); W row in registers, x row via
// wave-uniform loads (scalar pipe / broadcast cached).
__global__ __launch_bounds__(256) void xg0_gemm_k(
    const float* __restrict__ x, const float* __restrict__ Wih,
    const float* __restrict__ bih, const float* __restrict__ bhh,
    float* __restrict__ xg0)
{
  const int lane = threadIdx.x & 63;
  const int wid  = blockIdx.x * (blockDim.x >> 6) + (threadIdx.x >> 6);
  const int nw   = gridDim.x * (blockDim.x >> 6);
  float w[DDIM];
  #pragma unroll
  for (int d = 0; d < DDIM; ++d) w[d] = Wih[lane*DDIM + d];
  const float bias = bih[lane] + bhh[lane];
  for (int r = wid; r < NROWS; r += nw) {
    const int ru = __builtin_amdgcn_readfirstlane(r);
    const float* xr = x + (size_t)ru * DDIM;
    float a0 = bias, a1 = 0.f, a2 = 0.f, a3 = 0.f;
    #pragma unroll
    for (int d = 0; d < 56; d += 4) {
      a0 += xr[d]   * w[d];
      a1 += xr[d+1] * w[d+1];
      a2 += xr[d+2] * w[d+2];
      a3 += xr[d+3] * w[d+3];
    }
    a0 += xr[56] * w[56];
    xg0[(size_t)ru * 64 + lane] = (a0 + a1) + (a2 + a3);
  }
}

// One wave (64 lanes) per batch element. Lane g computes gate g of 64
// (i:0-15, f:16-31, g:32-47, o:48-63) for all 3 layers each timestep.
// h/c state replicated per channel (ch = lane&15) on all 4 gate groups.
// __launch_bounds__(64,1): 1 wave/EU minimum -> full 512-VGPR budget so the
// 80 weight floats stay in registers (VGPR=64 build spilled -> 32.8 GB scratch
// traffic, 2000 cyc/step).
__global__ __launch_bounds__(64, 1) void lstm_scan_k(
    const float* __restrict__ xg0,
    const int*   __restrict__ lengths,
    const float* __restrict__ Whh0,
    const float* __restrict__ Wih1, const float* __restrict__ Whh1,
    const float* __restrict__ bih1, const float* __restrict__ bhh1,
    const float* __restrict__ Wih2, const float* __restrict__ Whh2,
    const float* __restrict__ bih2, const float* __restrict__ bhh2,
    float* __restrict__ h2buf, float* __restrict__ accum)
{
  const int lane = threadIdx.x;
  const int b = blockIdx.x;
  const int len = lengths[b];
  const int ch = lane & 15;
  const bool isg = ((lane >> 4) == 2);

  float whh0[16], wih1[16], whh1[16], wih2[16], whh2[16];
  #pragma unroll
  for (int k = 0; k < 16; ++k) {
    whh0[k] = Whh0[lane*16 + k];
    wih1[k] = Wih1[lane*16 + k];
    whh1[k] = Whh1[lane*16 + k];
    wih2[k] = Wih2[lane*16 + k];
    whh2[k] = Whh2[lane*16 + k];
  }
  const float bias1 = bih1[lane] + bhh1[lane];
  const float bias2 = bih2[lane] + bhh2[lane];

  float h0=0.f,c0=0.f,h1=0.f,c1=0.f,h2=0.f,c2=0.f;
  float sum=0.f, sq=0.f;
  const int base = b*TT*64 + lane;
  float* __restrict__ h2row = h2buf + (size_t)b*TT*16;

  auto step = [&](float xg, int t) {
    // ---- layer 0 (input proj precomputed in xg) ----
    float a0 = xg, a1 = 0.f, a2 = 0.f, a3 = 0.f;
    #pragma unroll
    for (int k = 0; k < 16; k += 4) {
      a0 += whh0[k]   * bcastl(h0, k);
      a1 += whh0[k+1] * bcastl(h0, k+1);
      a2 += whh0[k+2] * bcastl(h0, k+2);
      a3 += whh0[k+3] * bcastl(h0, k+3);
    }
    float acc = (a0 + a1) + (a2 + a3);
    float arg = isg ? 2.f*acc : acc;
    float sg  = rcpf(1.f + __expf(-arg));
    float act = isg ? 2.f*sg - 1.f : sg;
    float gi = __shfl(act, ch,      64);
    float gf = __shfl(act, ch + 16, 64);
    float gg = __shfl(act, ch + 32, 64);
    float go = __shfl(act, ch + 48, 64);
    c0 = gf*c0 + gi*gg;
    h0 = go * (2.f*rcpf(1.f + __expf(-2.f*c0)) - 1.f);
    // ---- layer 1 ---- (8 accumulators: dependent-FMA depth 4)
    float p0 = bias1, p1 = 0.f, p2 = 0.f, p3 = 0.f;
    float p4 = 0.f, p5 = 0.f, p6 = 0.f, p7 = 0.f;
    #pragma unroll
    for (int k = 0; k < 16; k += 4) {
      p0 += wih1[k]   * bcastl(h0, k);
      p1 += wih1[k+1] * bcastl(h0, k+1);
      p2 += wih1[k+2] * bcastl(h0, k+2);
      p3 += wih1[k+3] * bcastl(h0, k+3);
      p4 += whh1[k]   * bcastl(h1, k);
      p5 += whh1[k+1] * bcastl(h1, k+1);
      p6 += whh1[k+2] * bcastl(h1, k+2);
      p7 += whh1[k+3] * bcastl(h1, k+3);
    }
    acc = ((p0 + p1) + (p2 + p3)) + ((p4 + p5) + (p6 + p7));
    arg = isg ? 2.f*acc : acc;
    sg  = rcpf(1.f + __expf(-arg));
    act = isg ? 2.f*sg - 1.f : sg;
    gi = __shfl(act, ch, 64); gf = __shfl(act, ch+16, 64);
    gg = __shfl(act, ch+32, 64); go = __shfl(act, ch+48, 64);
    c1 = gf*c1 + gi*gg;
    h1 = go * (2.f*rcpf(1.f + __expf(-2.f*c1)) - 1.f);
    // ---- layer 2 ----
    float q0 = bias2, q1 = 0.f, q2 = 0.f, q3 = 0.f;
    float q4 = 0.f, q5 = 0.f, q6 = 0.f, q7 = 0.f;
    #pragma unroll
    for (int k = 0; k < 16; k += 4) {
      q0 += wih2[k]   * bcastl(h1, k);
      q1 += wih2[k+1] * bcastl(h1, k+1);
      q2 += wih2[k+2] * bcastl(h1, k+2);
      q3 += wih2[k+3] * bcastl(h1, k+3);
      q4 += whh2[k]   * bcastl(h2, k);
      q5 += whh2[k+1] * bcastl(h2, k+1);
      q6 += whh2[k+2] * bcastl(h2, k+2);
      q7 += whh2[k+3] * bcastl(h2, k+3);
    }
    acc = ((q0 + q1) + (q2 + q3)) + ((q4 + q5) + (q6 + q7));
    arg = isg ? 2.f*acc : acc;
    sg  = rcpf(1.f + __expf(-arg));
    act = isg ? 2.f*sg - 1.f : sg;
    gi = __shfl(act, ch, 64); gf = __shfl(act, ch+16, 64);
    gg = __shfl(act, ch+32, 64); go = __shfl(act, ch+48, 64);
    c2 = gf*c2 + gi*gg;
    h2 = go * (2.f*rcpf(1.f + __expf(-2.f*c2)) - 1.f);

    if (lane < 16) h2row[t*16 + lane] = h2;
    sum += h2; sq += h2*h2;
  };

  // software prefetch, distance 4 steps
  float pf0 = xg0[base];
  float pf1 = xg0[base + 64];
  float pf2 = xg0[base + 128];
  float pf3 = xg0[base + 192];

  int t = 0;
  while (t + 4 <= len) {
    const int t4 = t + 4;
    int i0 = t4     > TT-1 ? TT-1 : t4;
    int i1 = t4 + 1 > TT-1 ? TT-1 : t4+1;
    int i2 = t4 + 2 > TT-1 ? TT-1 : t4+2;
    int i3 = t4 + 3 > TT-1 ? TT-1 : t4+3;
    float nf0 = xg0[base + i0*64];
    float nf1 = xg0[base + i1*64];
    float nf2 = xg0[base + i2*64];
    float nf3 = xg0[base + i3*64];
    step(pf0, t); step(pf1, t+1); step(pf2, t+2); step(pf3, t+3);
    pf0 = nf0; pf1 = nf1; pf2 = nf2; pf3 = nf3;
    t = t4;
  }
  for (; t < len; ++t) {       // <=3 tail steps, data already prefetched
    step(pf0, t);
    pf0 = pf1; pf1 = pf2; pf2 = pf3;
  }

  // zero padded region (masked positions) — coalesced full-wave stores
  for (int idx = len*16 + lane; idx < TT*16; idx += 64)
    h2row[idx] = 0.f;

  if (lane < 16) {
    atomicAdd(&accum[lane],      sum);
    atomicAdd(&accum[16 + lane], sq);
  }
}

// Fold BN (training-mode stats incl. padding zeros) + gamma/beta into FC:
// coef[o*16+c] = s_c * fc_w[o,c];  coef[64+o] = fc_b[o] + sum_c tb_c*fc_w[o,c]
__global__ void prep_k(const float* __restrict__ accum,
                       const float* __restrict__ gamma, const float* __restrict__ beta,
                       const float* __restrict__ fcw, const float* __restrict__ fcb,
                       float* __restrict__ coef)
{
  const int lane = threadIdx.x;          // 64 threads: o=lane>>4, c=lane&15
  const int o = lane >> 4, c = lane & 15;
  const float inv_n = 1.0f / NF;
  float mean = accum[c] * inv_n;
  float var  = accum[16 + c] * inv_n - mean*mean;
  float s  = gamma[c] * rsqrtf(var + 1e-5f);
  float tb = beta[c] - mean * s;
  float woc = fcw[o*16 + c];
  coef[lane] = s * woc;
  float term = tb * woc;
  #pragma unroll
  for (int off = 1; off < 16; off <<= 1) term += __shfl_xor(term, off, 16);
  if (c == 0) coef[64 + o] = fcb[o] + term;
}

__global__ __launch_bounds__(256) void finalize_k(
    const float* __restrict__ h2buf, const float* __restrict__ coef,
    float* __restrict__ out)
{
  const int r = blockIdx.x * 256 + threadIdx.x;
  const float4* hp = (const float4*)(h2buf + (size_t)r * 16);
  float4 v0 = hp[0], v1 = hp[1], v2 = hp[2], v3 = hp[3];
  float hv[16] = {v0.x,v0.y,v0.z,v0.w, v1.x,v1.y,v1.z,v1.w,
                  v2.x,v2.y,v2.z,v2.w, v3.x,v3.y,v3.z,v3.w};
  float4 o4;
  float* op = &o4.x;
  #pragma unroll
  for (int o = 0; o < 4; ++o) {
    float a = coef[64 + o];
    #pragma unroll
    for (int c = 0; c < 16; ++c) a += coef[o*16 + c] * hv[c];
    op[o] = a;
  }
  ((float4*)out)[r] = o4;
}

extern "C" void kernel_launch(void* const* d_in, const int* in_sizes, int n_in,
                              void* d_out, int out_size, void* d_ws, size_t ws_size,
                              hipStream_t stream)
{
  const float* x     = (const float*)d_in[0];
  const int* lengths = (const int*)d_in[1];
  const float* W_ih0 = (const float*)d_in[2];
  const float* W_hh0 = (const float*)d_in[3];
  const float* b_ih0 = (const float*)d_in[4];
  const float* b_hh0 = (const float*)d_in[5];
  const float* W_ih1 = (const float*)d_in[6];
  const float* W_hh1 = (const float*)d_in[7];
  const float* b_ih1 = (const float*)d_in[8];
  const float* b_hh1 = (const float*)d_in[9];
  const float* W_ih2 = (const float*)d_in[10];
  const float* W_hh2 = (const float*)d_in[11];
  const float* b_ih2 = (const float*)d_in[12];
  const float* b_hh2 = (const float*)d_in[13];
  const float* gamma = (const float*)d_in[14];
  const float* beta  = (const float*)d_in[15];
  const float* fcw   = (const float*)d_in[16];
  const float* fcb   = (const float*)d_in[17];
  float* out = (float*)d_out;

  float* ws    = (float*)d_ws;
  float* xg0   = ws;                        // B*T*64  = 33,554,432 floats (128 MB)
  float* h2    = ws + 33554432;             // B*T*16  =  8,388,608 floats (32 MB)
  float* accum = ws + 33554432 + 8388608;   // 32 floats
  float* coef  = accum + 32;                // 68 floats

  hipLaunchKernelGGL(zero_accum_k, dim3(1), dim3(32), 0, stream, accum);
  hipLaunchKernelGGL(xg0_gemm_k, dim3(1024), dim3(256), 0, stream,
                     x, W_ih0, b_ih0, b_hh0, xg0);
  hipLaunchKernelGGL(lstm_scan_k, dim3(256), dim3(64), 0, stream,
                     xg0, lengths, W_hh0, W_ih1, W_hh1, b_ih1, b_hh1,
                     W_ih2, W_hh2, b_ih2, b_hh2, h2, accum);
  hipLaunchKernelGGL(prep_k, dim3(1), dim3(64), 0, stream,
                     accum, gamma, beta, fcw, fcb, coef);
  hipLaunchKernelGGL(finalize_k, dim3(2048), dim3(256), 0, stream, h2, coef, out);
}

// Round 3
// 1202.840 us; speedup vs baseline: 1.7318x; 1.7318x over previous
//
#include <hip/hip_runtime.h>
#include <math.h>

#define TT 2048
#define BBATCH 256
#define DDIM 57
#define NROWS (BBATCH*TT)
#define NF 524288.0f

__device__ __forceinline__ float bcastl(float v, int k) {
  // wave-wide broadcast of lane k's value via the scalar pipe (SGPR result)
  return __uint_as_float((unsigned)__builtin_amdgcn_readlane((int)__float_as_uint(v), k));
}
__device__ __forceinline__ float rcpf(float x) { return __builtin_amdgcn_rcpf(x); }

__global__ void zero_accum_k(float* accum) {
  accum[threadIdx.x] = 0.f;
}

// xg0[r, g] = sum_d x[r,d] * W_ih0[g,d] + (b_ih0[g] + b_hh0[g])
__global__ __launch_bounds__(256) void xg0_gemm_k(
    const float* __restrict__ x, const float* __restrict__ Wih,
    const float* __restrict__ bih, const float* __restrict__ bhh,
    float* __restrict__ xg0)
{
  const int lane = threadIdx.x & 63;
  const int wid  = blockIdx.x * (blockDim.x >> 6) + (threadIdx.x >> 6);
  const int nw   = gridDim.x * (blockDim.x >> 6);
  float w[DDIM];
  #pragma unroll
  for (int d = 0; d < DDIM; ++d) w[d] = Wih[lane*DDIM + d];
  const float bias = bih[lane] + bhh[lane];
  for (int r = wid; r < NROWS; r += nw) {
    const int ru = __builtin_amdgcn_readfirstlane(r);
    const float* xr = x + (size_t)ru * DDIM;
    float a0 = bias, a1 = 0.f, a2 = 0.f, a3 = 0.f;
    #pragma unroll
    for (int d = 0; d < 56; d += 4) {
      a0 += xr[d]   * w[d];
      a1 += xr[d+1] * w[d+1];
      a2 += xr[d+2] * w[d+2];
      a3 += xr[d+3] * w[d+3];
    }
    a0 += xr[56] * w[56];
    xg0[(size_t)ru * 64 + lane] = (a0 + a1) + (a2 + a3);
  }
}

// Layer-pipelined scan: one block (3 waves) per batch element.
// Wave w owns layer w: in slot s, wave0 computes h0(s), wave1 h1(s-1),
// wave2 h2(s-2). h crosses waves via a 2-deep LDS double buffer, one
// __syncthreads per slot. Per-wave weight footprint: <=32 floats -> fits
// the 64-VGPR budget with NO spill (the 1-wave version's 80 floats spilled
// to scratch -> ~2000 cyc/step at L2 latency).
__global__ __launch_bounds__(192, 1) void lstm_scan_pipe_k(
    const float* __restrict__ xg0,
    const int*   __restrict__ lengths,
    const float* __restrict__ Whh0,
    const float* __restrict__ Wih1, const float* __restrict__ Whh1,
    const float* __restrict__ bih1, const float* __restrict__ bhh1,
    const float* __restrict__ Wih2, const float* __restrict__ Whh2,
    const float* __restrict__ bih2, const float* __restrict__ bhh2,
    float* __restrict__ h2buf, float* __restrict__ accum)
{
  const int tid  = threadIdx.x;
  const int wave = tid >> 6;       // 0,1,2 = layer index
  const int lane = tid & 63;       // gate index: i:0-15 f:16-31 g:32-47 o:48-63
  const int b    = blockIdx.x;
  const int len  = lengths[b];
  const int ch   = lane & 15;
  const bool isg = ((lane >> 4) == 2);

  __shared__ float lds_h0[2][16];
  __shared__ float lds_h1[2][16];

  // per-wave weights: wave0: wa=Whh0; wave1: wa=Wih1, wb=Whh1; wave2: wa=Wih2, wb=Whh2
  float wa[16], wb[16];
  float bias = 0.f;
  if (wave == 0) {
    #pragma unroll
    for (int k = 0; k < 16; ++k) { wa[k] = Whh0[lane*16 + k]; wb[k] = 0.f; }
  } else if (wave == 1) {
    #pragma unroll
    for (int k = 0; k < 16; ++k) { wa[k] = Wih1[lane*16 + k]; wb[k] = Whh1[lane*16 + k]; }
    bias = bih1[lane] + bhh1[lane];
  } else {
    #pragma unroll
    for (int k = 0; k < 16; ++k) { wa[k] = Wih2[lane*16 + k]; wb[k] = Whh2[lane*16 + k]; }
    bias = bih2[lane] + bhh2[lane];
  }

  float hs = 0.f, cs = 0.f;        // own-layer h (replicated per ch) and c
  float sum = 0.f, sq = 0.f;       // wave2 BN partials
  const int base = b*TT*64 + lane;
  float* __restrict__ h2row = h2buf + (size_t)b*TT*16;

  auto activate = [&](float acc) {
    float arg = isg ? 2.f*acc : acc;
    float sg  = rcpf(1.f + __expf(-arg));
    return isg ? 2.f*sg - 1.f : sg;
  };
  auto tanh2 = [&](float x) { return 2.f*rcpf(1.f + __expf(-2.f*x)) - 1.f; };

  // wave0 xg prefetch pipeline, distance 4 slots
  float pf0 = 0.f, pf1 = 0.f, pf2 = 0.f, pf3 = 0.f;
  if (wave == 0) {
    pf0 = xg0[base];
    pf1 = xg0[base + 64];
    pf2 = xg0[base + 128];
    pf3 = xg0[base + 192];
  }

  const int S = len + 2;
  for (int s = 0; s < S; ++s) {
    const int p = s & 1, q = p ^ 1;
    if (wave == 0) {
      if (s < len) {
        int ip = s + 4; ip = ip > TT-1 ? TT-1 : ip;
        float nf = xg0[base + ip*64];          // issue early, used 4 slots later
        float a0 = pf0, a1 = 0.f, a2 = 0.f, a3 = 0.f;
        #pragma unroll
        for (int k = 0; k < 16; k += 4) {
          a0 += wa[k]   * bcastl(hs, k);
          a1 += wa[k+1] * bcastl(hs, k+1);
          a2 += wa[k+2] * bcastl(hs, k+2);
          a3 += wa[k+3] * bcastl(hs, k+3);
        }
        float act = activate((a0 + a1) + (a2 + a3));
        float gi = __shfl(act, ch,      64);
        float gf = __shfl(act, ch + 16, 64);
        float gg = __shfl(act, ch + 32, 64);
        float go = __shfl(act, ch + 48, 64);
        cs = gf*cs + gi*gg;
        hs = go * tanh2(cs);
        if (lane < 16) lds_h0[p][lane] = hs;
        pf0 = pf1; pf1 = pf2; pf2 = pf3; pf3 = nf;
      }
    } else if (wave == 1) {
      if (s >= 1 && s <= len) {
        float hin = lds_h0[q][ch];             // h0(s-1); issue first,
        float p4 = 0.f, p5 = 0.f, p6 = 0.f, p7 = 0.f;
        #pragma unroll
        for (int k = 0; k < 16; k += 4) {      // overlap latency with whh part
          p4 += wb[k]   * bcastl(hs, k);
          p5 += wb[k+1] * bcastl(hs, k+1);
          p6 += wb[k+2] * bcastl(hs, k+2);
          p7 += wb[k+3] * bcastl(hs, k+3);
        }
        float p0 = bias, p1 = 0.f, p2 = 0.f, p3 = 0.f;
        #pragma unroll
        for (int k = 0; k < 16; k += 4) {
          p0 += wa[k]   * bcastl(hin, k);
          p1 += wa[k+1] * bcastl(hin, k+1);
          p2 += wa[k+2] * bcastl(hin, k+2);
          p3 += wa[k+3] * bcastl(hin, k+3);
        }
        float act = activate(((p0+p1)+(p2+p3)) + ((p4+p5)+(p6+p7)));
        float gi = __shfl(act, ch,      64);
        float gf = __shfl(act, ch + 16, 64);
        float gg = __shfl(act, ch + 32, 64);
        float go = __shfl(act, ch + 48, 64);
        cs = gf*cs + gi*gg;
        hs = go * tanh2(cs);
        if (lane < 16) lds_h1[p][lane] = hs;
      }
    } else {
      if (s >= 2) {                            // s <= len+1 by loop bound
        const int t = s - 2;
        float hin = lds_h1[q][ch];             // h1(s-2)
        float p4 = 0.f, p5 = 0.f, p6 = 0.f, p7 = 0.f;
        #pragma unroll
        for (int k = 0; k < 16; k += 4) {
          p4 += wb[k]   * bcastl(hs, k);
          p5 += wb[k+1] * bcastl(hs, k+1);
          p6 += wb[k+2] * bcastl(hs, k+2);
          p7 += wb[k+3] * bcastl(hs, k+3);
        }
        float p0 = bias, p1 = 0.f, p2 = 0.f, p3 = 0.f;
        #pragma unroll
        for (int k = 0; k < 16; k += 4) {
          p0 += wa[k]   * bcastl(hin, k);
          p1 += wa[k+1] * bcastl(hin, k+1);
          p2 += wa[k+2] * bcastl(hin, k+2);
          p3 += wa[k+3] * bcastl(hin, k+3);
        }
        float act = activate(((p0+p1)+(p2+p3)) + ((p4+p5)+(p6+p7)));
        float gi = __shfl(act, ch,      64);
        float gf = __shfl(act, ch + 16, 64);
        float gg = __shfl(act, ch + 32, 64);
        float go = __shfl(act, ch + 48, 64);
        cs = gf*cs + gi*gg;
        hs = go * tanh2(cs);
        if (lane < 16) h2row[t*16 + lane] = hs;
        sum += hs; sq += hs*hs;
      }
    }
    __syncthreads();
  }

  // zero padded region (masked positions) — all 192 threads
  for (int idx = len*16 + tid; idx < TT*16; idx += 192)
    h2row[idx] = 0.f;

  if (wave == 2 && lane < 16) {
    atomicAdd(&accum[lane],      sum);
    atomicAdd(&accum[16 + lane], sq);
  }
}

// Fold BN (training-mode stats incl. padding zeros) + gamma/beta into FC:
// coef[o*16+c] = s_c * fc_w[o,c];  coef[64+o] = fc_b[o] + sum_c tb_c*fc_w[o,c]
__global__ void prep_k(const float* __restrict__ accum,
                       const float* __restrict__ gamma, const float* __restrict__ beta,
                       const float* __restrict__ fcw, const float* __restrict__ fcb,
                       float* __restrict__ coef)
{
  const int lane = threadIdx.x;          // 64 threads: o=lane>>4, c=lane&15
  const int o = lane >> 4, c = lane & 15;
  const float inv_n = 1.0f / NF;
  float mean = accum[c] * inv_n;
  float var  = accum[16 + c] * inv_n - mean*mean;
  float s  = gamma[c] * rsqrtf(var + 1e-5f);
  float tb = beta[c] - mean * s;
  float woc = fcw[o*16 + c];
  coef[lane] = s * woc;
  float term = tb * woc;
  #pragma unroll
  for (int off = 1; off < 16; off <<= 1) term += __shfl_xor(term, off, 16);
  if (c == 0) coef[64 + o] = fcb[o] + term;
}

__global__ __launch_bounds__(256) void finalize_k(
    const float* __restrict__ h2buf, const float* __restrict__ coef,
    float* __restrict__ out)
{
  const int r = blockIdx.x * 256 + threadIdx.x;
  const float4* hp = (const float4*)(h2buf + (size_t)r * 16);
  float4 v0 = hp[0], v1 = hp[1], v2 = hp[2], v3 = hp[3];
  float hv[16] = {v0.x,v0.y,v0.z,v0.w, v1.x,v1.y,v1.z,v1.w,
                  v2.x,v2.y,v2.z,v2.w, v3.x,v3.y,v3.z,v3.w};
  float4 o4;
  float* op = &o4.x;
  #pragma unroll
  for (int o = 0; o < 4; ++o) {
    float a = coef[64 + o];
    #pragma unroll
    for (int c = 0; c < 16; ++c) a += coef[o*16 + c] * hv[c];
    op[o] = a;
  }
  ((float4*)out)[r] = o4;
}

extern "C" void kernel_launch(void* const* d_in, const int* in_sizes, int n_in,
                              void* d_out, int out_size, void* d_ws, size_t ws_size,
                              hipStream_t stream)
{
  const float* x     = (const float*)d_in[0];
  const int* lengths = (const int*)d_in[1];
  const float* W_ih0 = (const float*)d_in[2];
  const float* W_hh0 = (const float*)d_in[3];
  const float* b_ih0 = (const float*)d_in[4];
  const float* b_hh0 = (const float*)d_in[5];
  const float* W_ih1 = (const float*)d_in[6];
  const float* W_hh1 = (const float*)d_in[7];
  const float* b_ih1 = (const float*)d_in[8];
  const float* b_hh1 = (const float*)d_in[9];
  const float* W_ih2 = (const float*)d_in[10];
  const float* W_hh2 = (const float*)d_in[11];
  const float* b_ih2 = (const float*)d_in[12];
  const float* b_hh2 = (const float*)d_in[13];
  const float* gamma = (const float*)d_in[14];
  const float* beta  = (const float*)d_in[15];
  const float* fcw   = (const float*)d_in[16];
  const float* fcb   = (const float*)d_in[17];
  float* out = (float*)d_out;

  float* ws    = (float*)d_ws;
  float* xg0   = ws;                        // B*T*64  = 33,554,432 floats (128 MB)
  float* h2    = ws + 33554432;             // B*T*16  =  8,388,608 floats (32 MB)
  float* accum = ws + 33554432 + 8388608;   // 32 floats
  float* coef  = accum + 32;                // 68 floats

  hipLaunchKernelGGL(zero_accum_k, dim3(1), dim3(32), 0, stream, accum);
  hipLaunchKernelGGL(xg0_gemm_k, dim3(1024), dim3(256), 0, stream,
                     x, W_ih0, b_ih0, b_hh0, xg0);
  hipLaunchKernelGGL(lstm_scan_pipe_k, dim3(256), dim3(192), 0, stream,
                     xg0, lengths, W_hh0, W_ih1, W_hh1, b_ih1, b_hh1,
                     W_ih2, W_hh2, b_ih2, b_hh2, h2, accum);
  hipLaunchKernelGGL(prep_k, dim3(1), dim3(64), 0, stream,
                     accum, gamma, beta, fcw, fcb, coef);
  hipLaunchKernelGGL(finalize_k, dim3(2048), dim3(256), 0, stream, h2, coef, out);
}

// Round 4
// 838.961 us; speedup vs baseline: 2.4830x; 1.4337x over previous
//
#include <hip/hip_runtime.h>
#include <math.h>

#define TT 2048
#define BBATCH 256
#define DDIM 57
#define NROWS (BBATCH*TT)
#define NF 524288.0f
#define U 4

__device__ __forceinline__ float bcastl(float v, int k) {
  // wave-wide broadcast of lane k's value via readlane (SGPR result, scalar pipe)
  return __uint_as_float((unsigned)__builtin_amdgcn_readlane((int)__float_as_uint(v), k));
}
__device__ __forceinline__ float rcpf(float x) { return __builtin_amdgcn_rcpf(x); }

// quad_perm broadcast: all 4 lanes of each quad get lane (PAT&3)'s value.
// VALU DPP op (~3 cyc) vs ds_bpermute (~85 cyc LDS pipe).
template<int PAT>
__device__ __forceinline__ float quadb(float v) {
  return __int_as_float(__builtin_amdgcn_update_dpp(0, __float_as_int(v), PAT, 0xF, 0xF, true));
}

__global__ void zero_accum_k(float* accum) {
  accum[threadIdx.x] = 0.f;
}

// xg0[r, lane] = dot(x[r,:], W_ih0[g(lane),:]) + bias[g(lane)]
// lane->gate mapping matches the scan: g = (lane&3)*16 + (lane>>2)
// x row loaded coalesced by lanes 0..56, broadcast via readlane.
__global__ __launch_bounds__(256) void xg0_gemm_k(
    const float* __restrict__ x, const float* __restrict__ Wih,
    const float* __restrict__ bih, const float* __restrict__ bhh,
    float* __restrict__ xg0)
{
  const int lane = threadIdx.x & 63;
  const int g = (lane & 3) * 16 + (lane >> 2);
  const int wid  = blockIdx.x * (blockDim.x >> 6) + (threadIdx.x >> 6);
  const int nw   = gridDim.x * (blockDim.x >> 6);
  float w[DDIM];
  #pragma unroll
  for (int d = 0; d < DDIM; ++d) w[d] = Wih[g*DDIM + d];
  const float bias = bih[g] + bhh[g];
  for (int r = wid; r < NROWS; r += nw) {
    const int ru = __builtin_amdgcn_readfirstlane(r);
    float xv = 0.f;
    if (lane < DDIM) xv = x[(size_t)ru * DDIM + lane];  // coalesced 228B
    float a0 = bias, a1 = 0.f, a2 = 0.f, a3 = 0.f;
    #pragma unroll
    for (int d = 0; d < 56; d += 4) {
      a0 += w[d]   * bcastl(xv, d);
      a1 += w[d+1] * bcastl(xv, d+1);
      a2 += w[d+2] * bcastl(xv, d+2);
      a3 += w[d+3] * bcastl(xv, d+3);
    }
    a0 += w[56] * bcastl(xv, 56);
    xg0[(size_t)ru * 64 + lane] = (a0 + a1) + (a2 + a3);
  }
}

// Layer-pipelined scan, U=4 timesteps per slot. One block (3 waves) per batch
// element; wave w owns layer w, lagging w slots. Lane layout: ch=lane>>2,
// gate=lane&3 (i,f,g,o) -> gate gather is 4 DPP quad broadcasts (no LDS pipe).
// One __syncthreads per slot: the vmcnt(0) drain it implies is amortized over
// 4 steps and hidden because slot compute (~700cyc) > xg0 load latency.
__global__ __launch_bounds__(192, 1) void lstm_scan_pipe_k(
    const float* __restrict__ xg0,
    const int*   __restrict__ lengths,
    const float* __restrict__ Whh0,
    const float* __restrict__ Wih1, const float* __restrict__ Whh1,
    const float* __restrict__ bih1, const float* __restrict__ bhh1,
    const float* __restrict__ Wih2, const float* __restrict__ Whh2,
    const float* __restrict__ bih2, const float* __restrict__ bhh2,
    float* __restrict__ h2buf, float* __restrict__ accum)
{
  const int tid  = threadIdx.x;
  const int wave = tid >> 6;       // 0,1,2 = layer index
  const int lane = tid & 63;
  const int gt   = lane & 3;       // 0=i 1=f 2=g 3=o
  const int ch   = lane >> 2;      // channel 0..15
  const int g    = gt*16 + ch;     // weight row (PyTorch i,f,g,o blocks)
  const int b    = blockIdx.x;
  const int len  = lengths[b];
  const bool isg = (gt == 2);

  __shared__ float lds_h0[2][U][16];
  __shared__ float lds_h1[2][U][16];

  // wa = input weights (waves 1,2), wb = recurrent weights (all waves)
  float wa[16], wb[16];
  float bias = 0.f;
  if (wave == 0) {
    #pragma unroll
    for (int k = 0; k < 16; ++k) { wb[k] = Whh0[g*16 + k]; wa[k] = 0.f; }
  } else if (wave == 1) {
    #pragma unroll
    for (int k = 0; k < 16; ++k) { wa[k] = Wih1[g*16 + k]; wb[k] = Whh1[g*16 + k]; }
    bias = bih1[g] + bhh1[g];
  } else {
    #pragma unroll
    for (int k = 0; k < 16; ++k) { wa[k] = Wih2[g*16 + k]; wb[k] = Whh2[g*16 + k]; }
    bias = bih2[g] + bhh2[g];
  }

  float hs = 0.f, cs = 0.f;        // own-layer state, replicated across the quad
  float sum = 0.f, sq = 0.f;
  const int base = b*TT*64 + lane;
  float* __restrict__ h2row = h2buf + (size_t)b*TT*16;

  auto lstm_update = [&](float acc) {
    float arg = isg ? 2.f*acc : acc;
    float sg  = rcpf(1.f + __expf(-arg));
    float act = isg ? 2.f*sg - 1.f : sg;   // tanh for g-gate, sigmoid else
    float gi = quadb<0x00>(act);
    float gf = quadb<0x55>(act);
    float gg = quadb<0xAA>(act);
    float go = quadb<0xFF>(act);
    cs = gf*cs + gi*gg;
    hs = go * (2.f*rcpf(1.f + __expf(-2.f*cs)) - 1.f);
  };
  auto owndot = [&](float seed) {          // seed + Whh . h_own
    float a0 = seed, a1 = 0.f, a2 = 0.f, a3 = 0.f;
    #pragma unroll
    for (int k = 0; k < 16; k += 4) {      // h[k] lives on lane 4k
      a0 += wb[k]   * bcastl(hs, 4*k);
      a1 += wb[k+1] * bcastl(hs, 4*k+4);
      a2 += wb[k+2] * bcastl(hs, 4*k+8);
      a3 += wb[k+3] * bcastl(hs, 4*k+12);
    }
    return (a0 + a1) + (a2 + a3);
  };
  auto indot = [&](float hin) {            // bias + Wih . h_in
    float a0 = bias, a1 = 0.f, a2 = 0.f, a3 = 0.f;
    #pragma unroll
    for (int k = 0; k < 16; k += 4) {
      a0 += wa[k]   * bcastl(hin, 4*k);
      a1 += wa[k+1] * bcastl(hin, 4*k+4);
      a2 += wa[k+2] * bcastl(hin, 4*k+8);
      a3 += wa[k+3] * bcastl(hin, 4*k+12);
    }
    return (a0 + a1) + (a2 + a3);
  };

  const int NS = (len + U - 1) / U;        // producer (wave0) slot count
  const int S  = NS + 2;

  // wave0 prefetch: slots s and s+1 in registers, s+2 in flight
  float cur[U], nxt[U];
  if (wave == 0) {
    #pragma unroll
    for (int j = 0; j < U; ++j) cur[j] = xg0[base + j*64];
    #pragma unroll
    for (int j = 0; j < U; ++j) nxt[j] = xg0[base + (U + j)*64];
  }

  for (int s = 0; s < S; ++s) {
    const int p = s & 1, q = p ^ 1;
    if (wave == 0) {
      if (s < NS) {
        float ld[U];
        #pragma unroll
        for (int j = 0; j < U; ++j) {
          int ip = (s + 2)*U + j; ip = ip > TT-1 ? TT-1 : ip;
          ld[j] = xg0[base + ip*64];       // for slot s+2; drained at barrier,
        }                                   // hidden under ~700cyc of compute
        #pragma unroll
        for (int j = 0; j < U; ++j) {
          lstm_update(owndot(cur[j]));
          if (gt == 0) lds_h0[p][j][ch] = hs;
        }
        #pragma unroll
        for (int j = 0; j < U; ++j) { cur[j] = nxt[j]; nxt[j] = ld[j]; }
      }
    } else if (wave == 1) {
      if (s >= 1 && s <= NS) {
        float hin[U];
        #pragma unroll
        for (int j = 0; j < U; ++j) hin[j] = lds_h0[q][j][ch];
        float xin[U];
        #pragma unroll
        for (int j = 0; j < U; ++j) xin[j] = indot(hin[j]);  // off the serial chain
        #pragma unroll
        for (int j = 0; j < U; ++j) {
          lstm_update(owndot(xin[j]));
          if (gt == 0) lds_h1[p][j][ch] = hs;
        }
      }
    } else {
      if (s >= 2) {                        // s <= NS+1 by loop bound
        float hin[U];
        #pragma unroll
        for (int j = 0; j < U; ++j) hin[j] = lds_h1[q][j][ch];
        float xin[U];
        #pragma unroll
        for (int j = 0; j < U; ++j) xin[j] = indot(hin[j]);
        #pragma unroll
        for (int j = 0; j < U; ++j) {
          lstm_update(owndot(xin[j]));
          const int t = (s - 2)*U + j;
          if (t < len) {
            if (gt == 0) h2row[t*16 + ch] = hs;
            sum += hs; sq += hs*hs;
          }
        }
      }
    }
    __syncthreads();
  }

  // zero padded region (masked positions)
  for (int idx = len*16 + tid; idx < TT*16; idx += 192)
    h2row[idx] = 0.f;

  if (wave == 2 && gt == 0) {
    atomicAdd(&accum[ch],      sum);
    atomicAdd(&accum[16 + ch], sq);
  }
}

// Fold BN (training-mode stats incl. padding zeros) + gamma/beta into FC:
// coef[o*16+c] = s_c * fc_w[o,c];  coef[64+o] = fc_b[o] + sum_c tb_c*fc_w[o,c]
__global__ void prep_k(const float* __restrict__ accum,
                       const float* __restrict__ gamma, const float* __restrict__ beta,
                       const float* __restrict__ fcw, const float* __restrict__ fcb,
                       float* __restrict__ coef)
{
  const int lane = threadIdx.x;          // 64 threads: o=lane>>4, c=lane&15
  const int o = lane >> 4, c = lane & 15;
  const float inv_n = 1.0f / NF;
  float mean = accum[c] * inv_n;
  float var  = accum[16 + c] * inv_n - mean*mean;
  float s  = gamma[c] * rsqrtf(var + 1e-5f);
  float tb = beta[c] - mean * s;
  float woc = fcw[o*16 + c];
  coef[lane] = s * woc;
  float term = tb * woc;
  #pragma unroll
  for (int off = 1; off < 16; off <<= 1) term += __shfl_xor(term, off, 16);
  if (c == 0) coef[64 + o] = fcb[o] + term;
}

__global__ __launch_bounds__(256) void finalize_k(
    const float* __restrict__ h2buf, const float* __restrict__ coef,
    float* __restrict__ out)
{
  const int r = blockIdx.x * 256 + threadIdx.x;
  const float4* hp = (const float4*)(h2buf + (size_t)r * 16);
  float4 v0 = hp[0], v1 = hp[1], v2 = hp[2], v3 = hp[3];
  float hv[16] = {v0.x,v0.y,v0.z,v0.w, v1.x,v1.y,v1.z,v1.w,
                  v2.x,v2.y,v2.z,v2.w, v3.x,v3.y,v3.z,v3.w};
  float4 o4;
  float* op = &o4.x;
  #pragma unroll
  for (int o = 0; o < 4; ++o) {
    float a = coef[64 + o];
    #pragma unroll
    for (int c = 0; c < 16; ++c) a += coef[o*16 + c] * hv[c];
    op[o] = a;
  }
  ((float4*)out)[r] = o4;
}

extern "C" void kernel_launch(void* const* d_in, const int* in_sizes, int n_in,
                              void* d_out, int out_size, void* d_ws, size_t ws_size,
                              hipStream_t stream)
{
  const float* x     = (const float*)d_in[0];
  const int* lengths = (const int*)d_in[1];
  const float* W_ih0 = (const float*)d_in[2];
  const float* W_hh0 = (const float*)d_in[3];
  const float* b_ih0 = (const float*)d_in[4];
  const float* b_hh0 = (const float*)d_in[5];
  const float* W_ih1 = (const float*)d_in[6];
  const float* W_hh1 = (const float*)d_in[7];
  const float* b_ih1 = (const float*)d_in[8];
  const float* b_hh1 = (const float*)d_in[9];
  const float* W_ih2 = (const float*)d_in[10];
  const float* W_hh2 = (const float*)d_in[11];
  const float* b_ih2 = (const float*)d_in[12];
  const float* b_hh2 = (const float*)d_in[13];
  const float* gamma = (const float*)d_in[14];
  const float* beta  = (const float*)d_in[15];
  const float* fcw   = (const float*)d_in[16];
  const float* fcb   = (const float*)d_in[17];
  float* out = (float*)d_out;

  float* ws    = (float*)d_ws;
  float* xg0   = ws;                        // B*T*64  = 33,554,432 floats (128 MB)
  float* h2    = ws + 33554432;             // B*T*16  =  8,388,608 floats (32 MB)
  float* accum = ws + 33554432 + 8388608;   // 32 floats
  float* coef  = accum + 32;                // 68 floats

  hipLaunchKernelGGL(zero_accum_k, dim3(1), dim3(32), 0, stream, accum);
  hipLaunchKernelGGL(xg0_gemm_k, dim3(1024), dim3(256), 0, stream,
                     x, W_ih0, b_ih0, b_hh0, xg0);
  hipLaunchKernelGGL(lstm_scan_pipe_k, dim3(256), dim3(192), 0, stream,
                     xg0, lengths, W_hh0, W_ih1, W_hh1, b_ih1, b_hh1,
                     W_ih2, W_hh2, b_ih2, b_hh2, h2, accum);
  hipLaunchKernelGGL(prep_k, dim3(1), dim3(64), 0, stream,
                     accum, gamma, beta, fcw, fcb, coef);
  hipLaunchKernelGGL(finalize_k, dim3(2048), dim3(256), 0, stream, h2, coef, out);
}

// Round 5
// 813.602 us; speedup vs baseline: 2.5604x; 1.0312x over previous
//
#include <hip/hip_runtime.h>
#include <math.h>

#define TT 2048
#define BBATCH 256
#define DDIM 57
#define NROWS (BBATCH*TT)
#define NF 524288.0f
#define U 8

#define K1 (-1.4426950408889634f)   // -log2(e)   : sigmoid rows (i,f,o)
#define K2 (-2.8853900817779268f)   // -2 log2(e) : tanh rows (g) and tanh(c)

__device__ __forceinline__ float bcastl(float v, int k) {
  return __uint_as_float((unsigned)__builtin_amdgcn_readlane((int)__float_as_uint(v), k));
}
__device__ __forceinline__ float rcpf(float x) { return __builtin_amdgcn_rcpf(x); }
__device__ __forceinline__ float exp2f_(float x) { return __builtin_amdgcn_exp2f(x); }

// quad_perm broadcast: all 4 lanes of each quad get lane (PAT&3)'s value.
template<int PAT>
__device__ __forceinline__ float quadb(float v) {
  return __int_as_float(__builtin_amdgcn_update_dpp(0, __float_as_int(v), PAT, 0xF, 0xF, true));
}

__global__ void zero_accum_k(float* accum) {
  accum[threadIdx.x] = 0.f;
}

// xg0[r, lane] = fac(g) * (dot(x[r,:], W_ih0[g,:]) + b_ih0[g]+b_hh0[g])
// g = (lane&3)*16 + (lane>>2); fac = K2 for the g-gate rows else K1 (folds the
// exp2 conversion into the precomputed seed). Next-row x prefetched to hide
// the load->readlane stall; 2048 blocks -> 8 waves/SIMD for latency hiding.
__global__ __launch_bounds__(256) void xg0_gemm_k(
    const float* __restrict__ x, const float* __restrict__ Wih,
    const float* __restrict__ bih, const float* __restrict__ bhh,
    float* __restrict__ xg0)
{
  const int lane = threadIdx.x & 63;
  const int g = (lane & 3) * 16 + (lane >> 2);
  const float fac = ((lane & 3) == 2) ? K2 : K1;
  const int wid  = blockIdx.x * (blockDim.x >> 6) + (threadIdx.x >> 6);
  const int nw   = gridDim.x * (blockDim.x >> 6);
  float w[DDIM];
  #pragma unroll
  for (int d = 0; d < DDIM; ++d) w[d] = fac * Wih[g*DDIM + d];
  const float bias = fac * (bih[g] + bhh[g]);

  int r = wid;
  float xv = 0.f;
  if (r < NROWS && lane < DDIM)
    xv = x[(size_t)__builtin_amdgcn_readfirstlane(r) * DDIM + lane];
  for (; r < NROWS; r += nw) {
    const int rn = r + nw;
    float xn = 0.f;
    if (rn < NROWS && lane < DDIM)                  // prefetch next row
      xn = x[(size_t)__builtin_amdgcn_readfirstlane(rn) * DDIM + lane];
    float a0 = bias, a1 = 0.f, a2 = 0.f, a3 = 0.f;
    #pragma unroll
    for (int d = 0; d < 56; d += 4) {
      a0 += w[d]   * bcastl(xv, d);
      a1 += w[d+1] * bcastl(xv, d+1);
      a2 += w[d+2] * bcastl(xv, d+2);
      a3 += w[d+3] * bcastl(xv, d+3);
    }
    a0 += w[56] * bcastl(xv, 56);
    xg0[(size_t)__builtin_amdgcn_readfirstlane(r) * 64 + lane] = (a0 + a1) + (a2 + a3);
    xv = xn;
  }
}

// Layer-pipelined scan, U=8 steps/slot, 3 waves/block (wave w = layer w,
// lagging w slots). Lane layout: ch=lane>>2, gate=lane&3 (i,f,g,o).
// - input-dot h read as full vector via 4x same-address ds_read_b128
//   (broadcast) -> 16 pure-VGPR FMAs, no readlane.
// - own-dot via readlane (h in registers).
// - exp2 scaling folded into weights: act = rcp(1+exp2(dot)), g-gate 2s-1.
__global__ __launch_bounds__(192, 1) void lstm_scan_pipe_k(
    const float* __restrict__ xg0,
    const int*   __restrict__ lengths,
    const float* __restrict__ Whh0,
    const float* __restrict__ Wih1, const float* __restrict__ Whh1,
    const float* __restrict__ bih1, const float* __restrict__ bhh1,
    const float* __restrict__ Wih2, const float* __restrict__ Whh2,
    const float* __restrict__ bih2, const float* __restrict__ bhh2,
    float* __restrict__ h2buf, float* __restrict__ accum)
{
  const int tid  = threadIdx.x;
  const int wave = tid >> 6;
  const int lane = tid & 63;
  const int gt   = lane & 3;       // 0=i 1=f 2=g 3=o
  const int ch   = lane >> 2;      // channel 0..15
  const int g    = gt*16 + ch;     // weight row (PyTorch i,f,g,o blocks)
  const int b    = blockIdx.x;
  const int len  = lengths[b];
  const bool isg = (gt == 2);
  const float fac = isg ? K2 : K1;
  const float mg = isg ? 2.f : 1.f;     // act = s*mg + ag
  const float ag = isg ? -1.f : 0.f;

  __shared__ float lds_h0[2][U][16];
  __shared__ float lds_h1[2][U][16];

  float wa[16], wb[16];
  float bias = 0.f;
  if (wave == 0) {
    #pragma unroll
    for (int k = 0; k < 16; ++k) { wb[k] = fac * Whh0[g*16 + k]; wa[k] = 0.f; }
  } else if (wave == 1) {
    #pragma unroll
    for (int k = 0; k < 16; ++k) { wa[k] = fac * Wih1[g*16 + k]; wb[k] = fac * Whh1[g*16 + k]; }
    bias = fac * (bih1[g] + bhh1[g]);
  } else {
    #pragma unroll
    for (int k = 0; k < 16; ++k) { wa[k] = fac * Wih2[g*16 + k]; wb[k] = fac * Whh2[g*16 + k]; }
    bias = fac * (bih2[g] + bhh2[g]);
  }

  float hs = 0.f, cs = 0.f;
  float sum = 0.f, sq = 0.f;
  const int base = b*TT*64 + lane;
  float* __restrict__ h2row = h2buf + (size_t)b*TT*16;

  auto lstm_update = [&](float dot) {
    float s   = rcpf(1.f + exp2f_(dot));
    float act = fmaf(s, mg, ag);          // sigmoid, or tanh for g-gate
    float gi = quadb<0x00>(act);
    float gf = quadb<0x55>(act);
    float gg = quadb<0xAA>(act);
    float go = quadb<0xFF>(act);
    cs = fmaf(gf, cs, gi*gg);
    float r = rcpf(1.f + exp2f_(cs * K2));
    hs = go * fmaf(2.f, r, -1.f);         // go * tanh(cs)
  };
  auto owndot = [&](float seed) {         // seed + Whh' . h_own (readlane)
    float a0 = seed, a1 = 0.f, a2 = 0.f, a3 = 0.f;
    #pragma unroll
    for (int k = 0; k < 16; k += 4) {     // h[k] lives on lane 4k
      a0 += wb[k]   * bcastl(hs, 4*k);
      a1 += wb[k+1] * bcastl(hs, 4*k+4);
      a2 += wb[k+2] * bcastl(hs, 4*k+8);
      a3 += wb[k+3] * bcastl(hs, 4*k+12);
    }
    return (a0 + a1) + (a2 + a3);
  };
  // bias + Wih' . hin, hin as full register vector (no readlane)
  auto indot = [&](const float* hin) {
    float a0 = bias, a1 = 0.f, a2 = 0.f, a3 = 0.f;
    #pragma unroll
    for (int k = 0; k < 16; k += 4) {
      a0 += wa[k]   * hin[k];
      a1 += wa[k+1] * hin[k+1];
      a2 += wa[k+2] * hin[k+2];
      a3 += wa[k+3] * hin[k+3];
    }
    return (a0 + a1) + (a2 + a3);
  };

  const int NS = (len + U - 1) / U;
  const int S  = NS + 2;

  float cur[U], nxt[U];
  if (wave == 0) {
    #pragma unroll
    for (int j = 0; j < U; ++j) cur[j] = xg0[base + j*64];
    #pragma unroll
    for (int j = 0; j < U; ++j) {
      int ip = U + j; ip = ip > TT-1 ? TT-1 : ip;
      nxt[j] = xg0[base + ip*64];
    }
  }

  for (int s = 0; s < S; ++s) {
    const int p = s & 1, q = p ^ 1;
    if (wave == 0) {
      if (s < NS) {
        float ld[U];
        #pragma unroll
        for (int j = 0; j < U; ++j) {
          int ip = (s + 2)*U + j; ip = ip > TT-1 ? TT-1 : ip;
          ld[j] = xg0[base + ip*64];      // slot s+2; lands well before use
        }
        #pragma unroll
        for (int j = 0; j < U; ++j) {
          lstm_update(owndot(cur[j]));
          if (gt == 0) lds_h0[p][j][ch] = hs;
        }
        #pragma unroll
        for (int j = 0; j < U; ++j) { cur[j] = nxt[j]; nxt[j] = ld[j]; }
      }
    } else if (wave == 1) {
      if (s >= 1 && s <= NS) {
        #pragma unroll
        for (int j = 0; j < U; ++j) {
          // broadcast (same-address) vector read of h0(s-1, step j)
          const float4* hp = (const float4*)&lds_h0[q][j][0];
          float4 h0v = hp[0], h1v = hp[1], h2v = hp[2], h3v = hp[3];
          float hin[16] = {h0v.x,h0v.y,h0v.z,h0v.w, h1v.x,h1v.y,h1v.z,h1v.w,
                           h2v.x,h2v.y,h2v.z,h2v.w, h3v.x,h3v.y,h3v.z,h3v.w};
          lstm_update(owndot(indot(hin)));
          if (gt == 0) lds_h1[p][j][ch] = hs;
        }
      }
    } else {
      if (s >= 2) {
        #pragma unroll
        for (int j = 0; j < U; ++j) {
          const float4* hp = (const float4*)&lds_h1[q][j][0];
          float4 h0v = hp[0], h1v = hp[1], h2v = hp[2], h3v = hp[3];
          float hin[16] = {h0v.x,h0v.y,h0v.z,h0v.w, h1v.x,h1v.y,h1v.z,h1v.w,
                           h2v.x,h2v.y,h2v.z,h2v.w, h3v.x,h3v.y,h3v.z,h3v.w};
          lstm_update(owndot(indot(hin)));
          const int t = (s - 2)*U + j;
          if (t < len) {
            if (gt == 0) h2row[t*16 + ch] = hs;
            sum += hs; sq += hs*hs;
          }
        }
      }
    }
    __syncthreads();
  }

  for (int idx = len*16 + tid; idx < TT*16; idx += 192)
    h2row[idx] = 0.f;

  if (wave == 2 && gt == 0) {
    atomicAdd(&accum[ch],      sum);
    atomicAdd(&accum[16 + ch], sq);
  }
}

// Fold BN (training stats incl. padding zeros) + gamma/beta into FC.
__global__ void prep_k(const float* __restrict__ accum,
                       const float* __restrict__ gamma, const float* __restrict__ beta,
                       const float* __restrict__ fcw, const float* __restrict__ fcb,
                       float* __restrict__ coef)
{
  const int lane = threadIdx.x;
  const int o = lane >> 4, c = lane & 15;
  const float inv_n = 1.0f / NF;
  float mean = accum[c] * inv_n;
  float var  = accum[16 + c] * inv_n - mean*mean;
  float s  = gamma[c] * rsqrtf(var + 1e-5f);
  float tb = beta[c] - mean * s;
  float woc = fcw[o*16 + c];
  coef[lane] = s * woc;
  float term = tb * woc;
  #pragma unroll
  for (int off = 1; off < 16; off <<= 1) term += __shfl_xor(term, off, 16);
  if (c == 0) coef[64 + o] = fcb[o] + term;
}

__global__ __launch_bounds__(256) void finalize_k(
    const float* __restrict__ h2buf, const float* __restrict__ coef,
    float* __restrict__ out)
{
  const int r = blockIdx.x * 256 + threadIdx.x;
  const float4* hp = (const float4*)(h2buf + (size_t)r * 16);
  float4 v0 = hp[0], v1 = hp[1], v2 = hp[2], v3 = hp[3];
  float hv[16] = {v0.x,v0.y,v0.z,v0.w, v1.x,v1.y,v1.z,v1.w,
                  v2.x,v2.y,v2.z,v2.w, v3.x,v3.y,v3.z,v3.w};
  float4 o4;
  float* op = &o4.x;
  #pragma unroll
  for (int o = 0; o < 4; ++o) {
    float a = coef[64 + o];
    #pragma unroll
    for (int c = 0; c < 16; ++c) a += coef[o*16 + c] * hv[c];
    op[o] = a;
  }
  ((float4*)out)[r] = o4;
}

extern "C" void kernel_launch(void* const* d_in, const int* in_sizes, int n_in,
                              void* d_out, int out_size, void* d_ws, size_t ws_size,
                              hipStream_t stream)
{
  const float* x     = (const float*)d_in[0];
  const int* lengths = (const int*)d_in[1];
  const float* W_ih0 = (const float*)d_in[2];
  const float* W_hh0 = (const float*)d_in[3];
  const float* b_ih0 = (const float*)d_in[4];
  const float* b_hh0 = (const float*)d_in[5];
  const float* W_ih1 = (const float*)d_in[6];
  const float* W_hh1 = (const float*)d_in[7];
  const float* b_ih1 = (const float*)d_in[8];
  const float* b_hh1 = (const float*)d_in[9];
  const float* W_ih2 = (const float*)d_in[10];
  const float* W_hh2 = (const float*)d_in[11];
  const float* b_ih2 = (const float*)d_in[12];
  const float* b_hh2 = (const float*)d_in[13];
  const float* gamma = (const float*)d_in[14];
  const float* beta  = (const float*)d_in[15];
  const float* fcw   = (const float*)d_in[16];
  const float* fcb   = (const float*)d_in[17];
  float* out = (float*)d_out;

  float* ws    = (float*)d_ws;
  float* xg0   = ws;                        // B*T*64 floats (128 MB)
  float* h2    = ws + 33554432;             // B*T*16 floats (32 MB)
  float* accum = ws + 33554432 + 8388608;   // 32 floats
  float* coef  = accum + 32;                // 68 floats

  hipLaunchKernelGGL(zero_accum_k, dim3(1), dim3(32), 0, stream, accum);
  hipLaunchKernelGGL(xg0_gemm_k, dim3(2048), dim3(256), 0, stream,
                     x, W_ih0, b_ih0, b_hh0, xg0);
  hipLaunchKernelGGL(lstm_scan_pipe_k, dim3(256), dim3(192), 0, stream,
                     xg0, lengths, W_hh0, W_ih1, W_hh1, b_ih1, b_hh1,
                     W_ih2, W_hh2, b_ih2, b_hh2, h2, accum);
  hipLaunchKernelGGL(prep_k, dim3(1), dim3(64), 0, stream,
                     accum, gamma, beta, fcw, fcb, coef);
  hipLaunchKernelGGL(finalize_k, dim3(2048), dim3(256), 0, stream, h2, coef, out);
}